// Round 1
// baseline (1015.553 us; speedup 1.0000x reference)
//
#include <hip/hip_runtime.h>
#include <math.h>

#define D 64

// ---------------- Kernel 1: per-node linear transforms ----------------
// A = h@W_att, P = h@W_p, PP = h@W_pp, PHI = h@phi_w + phi_b, psi = h@fdef_w + fdef_b
__global__ __launch_bounds__(256) void node_pre_kernel(
    const float* __restrict__ h,
    const float* __restrict__ W_att,
    const float* __restrict__ W_p,
    const float* __restrict__ W_pp,
    const float* __restrict__ phi_w,
    const float* __restrict__ phi_b,
    const float* __restrict__ fdef_w,
    const float* __restrict__ fdef_b,
    float* __restrict__ A,
    float* __restrict__ P,
    float* __restrict__ PP,
    float* __restrict__ PHI,
    float* __restrict__ psi,
    int nNodes)
{
    __shared__ float sWatt[D * D];
    __shared__ float sWp[D * D];
    __shared__ float sWpp[D * D];
    __shared__ float sPhi[D * D];
    __shared__ float sPhib[D];
    __shared__ float sFdef[D];
    __shared__ float hrow[4][D];

    const int tid = threadIdx.x;
    for (int i = tid; i < D * D; i += 256) {
        sWatt[i] = W_att[i];
        sWp[i]   = W_p[i];
        sWpp[i]  = W_pp[i];
        sPhi[i]  = phi_w[i];
    }
    if (tid < D) { sPhib[tid] = phi_b[tid]; sFdef[tid] = fdef_w[tid]; }
    __syncthreads();
    const float fb = fdef_b[0];

    const int g = tid >> 6;   // wave id within block (0..3)
    const int j = tid & 63;   // output dim

    for (int n0 = blockIdx.x * 4; n0 < nNodes; n0 += gridDim.x * 4) {
        const int n = n0 + g;
        __syncthreads();
        if (n < nNodes) hrow[g][j] = h[(size_t)n * D + j];
        __syncthreads();
        if (n < nNodes) {
            float a = 0.f, p = 0.f, pp = 0.f, ph = sPhib[j];
            #pragma unroll 8
            for (int k = 0; k < D; ++k) {
                const float hk = hrow[g][k];
                a  += hk * sWatt[k * D + j];
                p  += hk * sWp[k * D + j];
                pp += hk * sWpp[k * D + j];
                ph += hk * sPhi[k * D + j];
            }
            const size_t base = (size_t)n * D + j;
            A[base]   = a;
            P[base]   = p;
            PP[base]  = pp;
            PHI[base] = ph;
            // psi[n] = dot(hrow, fdef) + fb  (wave reduce over 64 lanes)
            float ps = hrow[g][j] * sFdef[j];
            #pragma unroll
            for (int off = 32; off >= 1; off >>= 1) ps += __shfl_xor(ps, off, 64);
            if (j == 0) psi[n] = ps + fb;
        }
    }
}

// ---------------- Kernel 2: edge pass 1 (scores + segment denominators) ----------------
__global__ __launch_bounds__(256) void edge_pass1_kernel(
    const int* __restrict__ srcI,
    const int* __restrict__ tgtI,
    const float* __restrict__ h,
    const float* __restrict__ A,
    const float* __restrict__ P,
    const float* __restrict__ PP,
    const float* __restrict__ psi,
    float* __restrict__ alpha_num,
    float* __restrict__ alpha_den,
    float* __restrict__ beta_den,
    float* __restrict__ sum_num,
    int nEdges)
{
    const int lane = threadIdx.x & 15;   // 16 lanes per edge, float4 each => 64 dims
    const int egrp = threadIdx.x >> 4;   // 16 edges per block-iteration
    const int stride = gridDim.x * 16;

    for (int e = blockIdx.x * 16 + egrp; e < nEdges; e += stride) {
        const int s = srcI[e];
        const int t = tgtI[e];
        const float4 ht  = ((const float4*)(h  + (size_t)t * D))[lane];
        const float4 as  = ((const float4*)(A  + (size_t)s * D))[lane];
        const float4 ps  = ((const float4*)(P  + (size_t)s * D))[lane];
        const float4 ppt = ((const float4*)(PP + (size_t)t * D))[lane];

        float acc1 = ht.x * as.x + ht.y * as.y + ht.z * as.z + ht.w * as.w;
        float acc2 = ps.x * ppt.x + ps.y * ppt.y + ps.z * ppt.z + ps.w * ppt.w;

        // structural dot over dims 0..5 (s_feat = h[:, :6])
        if (lane < 2) {
            const float4 hs = ((const float4*)(h + (size_t)s * D))[lane];
            float sd = hs.x * ht.x + hs.y * ht.y;          // lane0: dims 0,1; lane1: dims 4,5
            if (lane == 0) sd += hs.z * ht.z + hs.w * ht.w; // dims 2,3
            acc1 += sd;
        }

        #pragma unroll
        for (int off = 8; off >= 1; off >>= 1) {
            acc1 += __shfl_xor(acc1, off, 64);
            acc2 += __shfl_xor(acc2, off, 64);
        }

        if (lane == 0) {
            const float an = __expf(acc1);
            const float bn = __expf(acc2);
            alpha_num[e] = an;
            atomicAdd(&alpha_den[t], an);
            atomicAdd(&beta_den[s], bn);
            atomicAdd(&sum_num[s], bn * __expf(-psi[t]));
        }
    }
}

// ---------------- Kernel 3: per-node mid (rho, inverse denominators) ----------------
__global__ __launch_bounds__(256) void node_mid_kernel(
    const float* __restrict__ alpha_den,
    const float* __restrict__ beta_den,
    const float* __restrict__ sum_num,
    float* __restrict__ inv_den,
    float* __restrict__ w1m,
    int nNodes)
{
    const int n = blockIdx.x * 256 + threadIdx.x;
    if (n >= nNodes) return;
    inv_den[n] = 1.0f / (alpha_den[n] + 1e-9f);
    const float st = sum_num[n] / (beta_den[n] + 1e-9f);
    const float d = -logf(st + 1e-8f);
    const float rho = 1.0f / (1.0f + __expf(-(d - 0.5f)));  // gamma=1, delta=0.5
    w1m[n] = 1.0f - rho;
}

// ---------------- Kernel 4: edge pass 2 (weighted message scatter) ----------------
__global__ __launch_bounds__(256) void edge_pass2_kernel(
    const int* __restrict__ srcI,
    const int* __restrict__ tgtI,
    const float* __restrict__ PHI,
    const float* __restrict__ alpha_num,
    const float* __restrict__ inv_den,
    const float* __restrict__ w1m,
    float* __restrict__ m_att,
    int nEdges)
{
    const int lane = threadIdx.x & 15;
    const int egrp = threadIdx.x >> 4;
    const int stride = gridDim.x * 16;

    for (int e = blockIdx.x * 16 + egrp; e < nEdges; e += stride) {
        const int s = srcI[e];
        const int t = tgtI[e];
        const float c = alpha_num[e] * inv_den[t] * w1m[s];
        const float4 ph = ((const float4*)(PHI + (size_t)s * D))[lane];
        float* mrow = m_att + (size_t)t * D + lane * 4;
        atomicAdd(mrow + 0, c * ph.x);
        atomicAdd(mrow + 1, c * ph.y);
        atomicAdd(mrow + 2, c * ph.z);
        atomicAdd(mrow + 3, c * ph.w);
    }
}

// ---------------- Kernel 5: final fused matmuls + relu + residual + LayerNorm ----------------
__global__ __launch_bounds__(256) void node_final_kernel(
    const float* __restrict__ h,
    const float* __restrict__ m_att,
    const float* __restrict__ W_self_w, const float* __restrict__ W_self_b,
    const float* __restrict__ W_A_w,    const float* __restrict__ W_A_b,
    const float* __restrict__ W_str_w,  const float* __restrict__ W_str_b,
    const float* __restrict__ ln_g,     const float* __restrict__ ln_b,
    float* __restrict__ out,
    int nNodes)
{
    __shared__ float sWs[D * D];
    __shared__ float sWa[D * D];
    __shared__ float sWstr[6 * D];
    __shared__ float sBias[D];
    __shared__ float sG[D], sB[D];
    __shared__ float hrow[4][D];
    __shared__ float mrow[4][D];

    const int tid = threadIdx.x;
    for (int i = tid; i < D * D; i += 256) { sWs[i] = W_self_w[i]; sWa[i] = W_A_w[i]; }
    for (int i = tid; i < 6 * D; i += 256) sWstr[i] = W_str_w[i];
    if (tid < D) {
        sBias[tid] = W_self_b[tid] + W_A_b[tid] + W_str_b[tid];
        sG[tid] = ln_g[tid];
        sB[tid] = ln_b[tid];
    }
    __syncthreads();

    const int g = tid >> 6, j = tid & 63;
    for (int n0 = blockIdx.x * 4; n0 < nNodes; n0 += gridDim.x * 4) {
        const int n = n0 + g;
        __syncthreads();
        if (n < nNodes) {
            hrow[g][j] = h[(size_t)n * D + j];
            mrow[g][j] = m_att[(size_t)n * D + j];
        }
        __syncthreads();
        if (n < nNodes) {
            float acc = sBias[j];
            #pragma unroll 8
            for (int k = 0; k < D; ++k)
                acc += hrow[g][k] * sWs[k * D + j] + mrow[g][k] * sWa[k * D + j];
            #pragma unroll
            for (int k = 0; k < 6; ++k)
                acc += hrow[g][k] * sWstr[k * D + j];

            float pre = fmaxf(acc, 0.f) + hrow[g][j];   // relu + residual

            // LayerNorm over the 64 lanes of this wave
            float mu = pre;
            #pragma unroll
            for (int off = 32; off >= 1; off >>= 1) mu += __shfl_xor(mu, off, 64);
            mu *= (1.0f / 64.0f);
            const float diff = pre - mu;
            float v = diff * diff;
            #pragma unroll
            for (int off = 32; off >= 1; off >>= 1) v += __shfl_xor(v, off, 64);
            v *= (1.0f / 64.0f);
            out[(size_t)n * D + j] = diff * rsqrtf(v + 1e-5f) * sG[j] + sB[j];
        }
    }
}

extern "C" void kernel_launch(void* const* d_in, const int* in_sizes, int n_in,
                              void* d_out, int out_size, void* d_ws, size_t ws_size,
                              hipStream_t stream) {
    const int* edge       = (const int*)d_in[0];
    const float* h        = (const float*)d_in[1];
    const float* W_att    = (const float*)d_in[2];
    const float* phi_w    = (const float*)d_in[3];
    const float* phi_b    = (const float*)d_in[4];
    const float* W_p      = (const float*)d_in[5];
    const float* W_pp     = (const float*)d_in[6];
    const float* fdef_w   = (const float*)d_in[7];
    const float* fdef_b   = (const float*)d_in[8];
    const float* W_self_w = (const float*)d_in[9];
    const float* W_self_b = (const float*)d_in[10];
    const float* W_A_w    = (const float*)d_in[11];
    const float* W_A_b    = (const float*)d_in[12];
    const float* W_str_w  = (const float*)d_in[13];
    const float* W_str_b  = (const float*)d_in[14];
    const float* ln_g     = (const float*)d_in[15];
    const float* ln_b     = (const float*)d_in[16];

    const int E = in_sizes[0] / 2;
    const int nNodes = in_sizes[1] / D;
    const int* srcI = edge;
    const int* tgtI = edge + E;

    float* ws = (float*)d_ws;
    size_t off = 0;
    float* m_att     = ws + off; off += (size_t)nNodes * D;
    float* alpha_den = ws + off; off += nNodes;
    float* beta_den  = ws + off; off += nNodes;
    float* sum_num   = ws + off; off += nNodes;
    const size_t zero_bytes = off * sizeof(float);
    float* A         = ws + off; off += (size_t)nNodes * D;
    float* P         = ws + off; off += (size_t)nNodes * D;
    float* PP        = ws + off; off += (size_t)nNodes * D;
    float* PHI       = ws + off; off += (size_t)nNodes * D;
    float* psi       = ws + off; off += nNodes;
    float* inv_den   = ws + off; off += nNodes;
    float* w1m       = ws + off; off += nNodes;
    float* alpha_num = ws + off; off += E;

    hipMemsetAsync(d_ws, 0, zero_bytes, stream);

    node_pre_kernel<<<2048, 256, 0, stream>>>(
        h, W_att, W_p, W_pp, phi_w, phi_b, fdef_w, fdef_b,
        A, P, PP, PHI, psi, nNodes);

    edge_pass1_kernel<<<8192, 256, 0, stream>>>(
        srcI, tgtI, h, A, P, PP, psi,
        alpha_num, alpha_den, beta_den, sum_num, E);

    node_mid_kernel<<<(nNodes + 255) / 256, 256, 0, stream>>>(
        alpha_den, beta_den, sum_num, inv_den, w1m, nNodes);

    edge_pass2_kernel<<<8192, 256, 0, stream>>>(
        srcI, tgtI, PHI, alpha_num, inv_den, w1m, m_att, E);

    node_final_kernel<<<2048, 256, 0, stream>>>(
        h, m_att, W_self_w, W_self_b, W_A_w, W_A_b,
        W_str_w, W_str_b, ln_g, ln_b, (float*)d_out, nNodes);
}

// Round 2
// 468.931 us; speedup vs baseline: 2.1657x; 2.1657x over previous
//
#include <hip/hip_runtime.h>
#include <math.h>

#define D 64

// ---------------- Kernel 1: per-node linear transforms ----------------
__global__ __launch_bounds__(256) void node_pre_kernel(
    const float* __restrict__ h,
    const float* __restrict__ W_att,
    const float* __restrict__ W_p,
    const float* __restrict__ W_pp,
    const float* __restrict__ phi_w,
    const float* __restrict__ phi_b,
    const float* __restrict__ fdef_w,
    const float* __restrict__ fdef_b,
    float* __restrict__ A,
    float* __restrict__ P,
    float* __restrict__ PP,
    float* __restrict__ PHI,
    float* __restrict__ psi,
    int nNodes)
{
    __shared__ float sWatt[D * D];
    __shared__ float sWp[D * D];
    __shared__ float sWpp[D * D];
    __shared__ float sPhi[D * D];
    __shared__ float sPhib[D];
    __shared__ float sFdef[D];
    __shared__ float hrow[4][D];

    const int tid = threadIdx.x;
    for (int i = tid; i < D * D; i += 256) {
        sWatt[i] = W_att[i];
        sWp[i]   = W_p[i];
        sWpp[i]  = W_pp[i];
        sPhi[i]  = phi_w[i];
    }
    if (tid < D) { sPhib[tid] = phi_b[tid]; sFdef[tid] = fdef_w[tid]; }
    __syncthreads();
    const float fb = fdef_b[0];

    const int g = tid >> 6;
    const int j = tid & 63;

    for (int n0 = blockIdx.x * 4; n0 < nNodes; n0 += gridDim.x * 4) {
        const int n = n0 + g;
        __syncthreads();
        if (n < nNodes) hrow[g][j] = h[(size_t)n * D + j];
        __syncthreads();
        if (n < nNodes) {
            float a = 0.f, p = 0.f, pp = 0.f, ph = sPhib[j];
            #pragma unroll 8
            for (int k = 0; k < D; ++k) {
                const float hk = hrow[g][k];
                a  += hk * sWatt[k * D + j];
                p  += hk * sWp[k * D + j];
                pp += hk * sWpp[k * D + j];
                ph += hk * sPhi[k * D + j];
            }
            const size_t base = (size_t)n * D + j;
            A[base]   = a;
            P[base]   = p;
            PP[base]  = pp;
            PHI[base] = ph;
            float ps = hrow[g][j] * sFdef[j];
            #pragma unroll
            for (int off = 32; off >= 1; off >>= 1) ps += __shfl_xor(ps, off, 64);
            if (j == 0) psi[n] = ps + fb;
        }
    }
}

// ---------------- CSR build: histogram + rank ----------------
__global__ __launch_bounds__(256) void hist_kernel(
    const int* __restrict__ tgtI, int* __restrict__ cnt, int* __restrict__ rank, int nEdges)
{
    const int e = blockIdx.x * 256 + threadIdx.x;
    if (e < nEdges) rank[e] = atomicAdd(&cnt[tgtI[e]], 1);
}

// ---------------- CSR build: single-block exclusive scan over cnt ----------------
__global__ __launch_bounds__(1024) void scan_kernel(
    const int* __restrict__ cnt, int* __restrict__ rowstart, int nNodes, int nEdges)
{
    __shared__ int sums[1024];
    const int tid = threadIdx.x;
    const int per = (nNodes + 1023) / 1024;
    const int beg = tid * per;
    const int end = min(beg + per, nNodes);
    int s = 0;
    for (int i = beg; i < end; ++i) s += cnt[i];
    sums[tid] = s;
    __syncthreads();
    for (int off = 1; off < 1024; off <<= 1) {
        int add = (tid >= off) ? sums[tid - off] : 0;
        __syncthreads();
        sums[tid] += add;
        __syncthreads();
    }
    int run = sums[tid] - s;   // exclusive prefix of this thread's chunk
    for (int i = beg; i < end; ++i) { rowstart[i] = run; run += cnt[i]; }
    if (tid == 1023) rowstart[nNodes] = nEdges;
}

// ---------------- Kernel 2: edge pass 1 (scores + segment denominators) ----------------
__global__ __launch_bounds__(256) void edge_pass1_kernel(
    const int* __restrict__ srcI,
    const int* __restrict__ tgtI,
    const float* __restrict__ h,
    const float* __restrict__ A,
    const float* __restrict__ P,
    const float* __restrict__ PP,
    const float* __restrict__ psi,
    float* __restrict__ alpha_num,
    float* __restrict__ alpha_den,
    float* __restrict__ beta_den,
    float* __restrict__ sum_num,
    int nEdges)
{
    const int lane = threadIdx.x & 15;
    const int egrp = threadIdx.x >> 4;
    const int stride = gridDim.x * 16;

    for (int e = blockIdx.x * 16 + egrp; e < nEdges; e += stride) {
        const int s = srcI[e];
        const int t = tgtI[e];
        const float4 ht  = ((const float4*)(h  + (size_t)t * D))[lane];
        const float4 as  = ((const float4*)(A  + (size_t)s * D))[lane];
        const float4 ps  = ((const float4*)(P  + (size_t)s * D))[lane];
        const float4 ppt = ((const float4*)(PP + (size_t)t * D))[lane];

        float acc1 = ht.x * as.x + ht.y * as.y + ht.z * as.z + ht.w * as.w;
        float acc2 = ps.x * ppt.x + ps.y * ppt.y + ps.z * ppt.z + ps.w * ppt.w;

        if (lane < 2) {
            const float4 hs = ((const float4*)(h + (size_t)s * D))[lane];
            float sd = hs.x * ht.x + hs.y * ht.y;
            if (lane == 0) sd += hs.z * ht.z + hs.w * ht.w;
            acc1 += sd;
        }

        #pragma unroll
        for (int off = 8; off >= 1; off >>= 1) {
            acc1 += __shfl_xor(acc1, off, 64);
            acc2 += __shfl_xor(acc2, off, 64);
        }

        if (lane == 0) {
            const float an = __expf(acc1);
            const float bn = __expf(acc2);
            alpha_num[e] = an;
            atomicAdd(&alpha_den[t], an);
            atomicAdd(&beta_den[s], bn);
            atomicAdd(&sum_num[s], bn * __expf(-psi[t]));
        }
    }
}

// ---------------- Kernel 3: per-node mid ----------------
__global__ __launch_bounds__(256) void node_mid_kernel(
    const float* __restrict__ alpha_den,
    const float* __restrict__ beta_den,
    const float* __restrict__ sum_num,
    float* __restrict__ inv_den,
    float* __restrict__ w1m,
    int nNodes)
{
    const int n = blockIdx.x * 256 + threadIdx.x;
    if (n >= nNodes) return;
    inv_den[n] = 1.0f / (alpha_den[n] + 1e-9f);
    const float st = sum_num[n] / (beta_den[n] + 1e-9f);
    const float d = -logf(st + 1e-8f);
    const float rho = 1.0f / (1.0f + __expf(-(d - 0.5f)));
    w1m[n] = 1.0f - rho;
}

// ---------------- CSR scatter: (src, coeff) sorted by tgt ----------------
__global__ __launch_bounds__(256) void scatter_kernel(
    const int* __restrict__ srcI,
    const int* __restrict__ tgtI,
    const int* __restrict__ rank,
    const int* __restrict__ rowstart,
    const float* __restrict__ alpha_num,
    const float* __restrict__ inv_den,
    const float* __restrict__ w1m,
    int* __restrict__ src_sorted,
    float* __restrict__ coeff_sorted,
    int nEdges)
{
    const int e = blockIdx.x * 256 + threadIdx.x;
    if (e >= nEdges) return;
    const int s = srcI[e];
    const int t = tgtI[e];
    const int pos = rowstart[t] + rank[e];
    src_sorted[pos]   = s;
    coeff_sorted[pos] = alpha_num[e] * inv_den[t] * w1m[s];
}

// ---------------- Kernel 4+5 fused: gather m_att + final matmuls + LN ----------------
__global__ __launch_bounds__(256) void gather_final_kernel(
    const int* __restrict__ rowstart,
    const int* __restrict__ src_sorted,
    const float* __restrict__ coeff_sorted,
    const float* __restrict__ PHI,
    const float* __restrict__ h,
    const float* __restrict__ W_self_w, const float* __restrict__ W_self_b,
    const float* __restrict__ W_A_w,    const float* __restrict__ W_A_b,
    const float* __restrict__ W_str_w,  const float* __restrict__ W_str_b,
    const float* __restrict__ ln_g,     const float* __restrict__ ln_b,
    float* __restrict__ out,
    int nNodes)
{
    __shared__ float sWs[D * D];
    __shared__ float sWa[D * D];
    __shared__ float sWstr[6 * D];
    __shared__ float sBias[D];
    __shared__ float sG[D], sB[D];
    __shared__ float hrow[4][D];
    __shared__ float mrow[4][D];

    const int tid = threadIdx.x;
    for (int i = tid; i < D * D; i += 256) { sWs[i] = W_self_w[i]; sWa[i] = W_A_w[i]; }
    for (int i = tid; i < 6 * D; i += 256) sWstr[i] = W_str_w[i];
    if (tid < D) {
        sBias[tid] = W_self_b[tid] + W_A_b[tid] + W_str_b[tid];
        sG[tid] = ln_g[tid];
        sB[tid] = ln_b[tid];
    }
    __syncthreads();

    const int g = tid >> 6, j = tid & 63;
    for (int n0 = blockIdx.x * 4; n0 < nNodes; n0 += gridDim.x * 4) {
        const int n = n0 + g;
        __syncthreads();
        if (n < nNodes) {
            // gather-reduce m_att row for node n: lane j owns dim j
            const int beg = rowstart[n];
            const int end = rowstart[n + 1];
            float acc = 0.f;
            int k = beg;
            for (; k + 3 < end; k += 4) {
                const int   s0 = src_sorted[k],     s1 = src_sorted[k + 1];
                const int   s2 = src_sorted[k + 2], s3 = src_sorted[k + 3];
                const float c0 = coeff_sorted[k],     c1 = coeff_sorted[k + 1];
                const float c2 = coeff_sorted[k + 2], c3 = coeff_sorted[k + 3];
                acc += c0 * PHI[(size_t)s0 * D + j] + c1 * PHI[(size_t)s1 * D + j]
                     + c2 * PHI[(size_t)s2 * D + j] + c3 * PHI[(size_t)s3 * D + j];
            }
            for (; k < end; ++k)
                acc += coeff_sorted[k] * PHI[(size_t)src_sorted[k] * D + j];
            mrow[g][j] = acc;
            hrow[g][j] = h[(size_t)n * D + j];
        }
        __syncthreads();
        if (n < nNodes) {
            float acc = sBias[j];
            #pragma unroll 8
            for (int k = 0; k < D; ++k)
                acc += hrow[g][k] * sWs[k * D + j] + mrow[g][k] * sWa[k * D + j];
            #pragma unroll
            for (int k = 0; k < 6; ++k)
                acc += hrow[g][k] * sWstr[k * D + j];

            float pre = fmaxf(acc, 0.f) + hrow[g][j];

            float mu = pre;
            #pragma unroll
            for (int off = 32; off >= 1; off >>= 1) mu += __shfl_xor(mu, off, 64);
            mu *= (1.0f / 64.0f);
            const float diff = pre - mu;
            float v = diff * diff;
            #pragma unroll
            for (int off = 32; off >= 1; off >>= 1) v += __shfl_xor(v, off, 64);
            v *= (1.0f / 64.0f);
            out[(size_t)n * D + j] = diff * rsqrtf(v + 1e-5f) * sG[j] + sB[j];
        }
    }
}

extern "C" void kernel_launch(void* const* d_in, const int* in_sizes, int n_in,
                              void* d_out, int out_size, void* d_ws, size_t ws_size,
                              hipStream_t stream) {
    const int* edge       = (const int*)d_in[0];
    const float* h        = (const float*)d_in[1];
    const float* W_att    = (const float*)d_in[2];
    const float* phi_w    = (const float*)d_in[3];
    const float* phi_b    = (const float*)d_in[4];
    const float* W_p      = (const float*)d_in[5];
    const float* W_pp     = (const float*)d_in[6];
    const float* fdef_w   = (const float*)d_in[7];
    const float* fdef_b   = (const float*)d_in[8];
    const float* W_self_w = (const float*)d_in[9];
    const float* W_self_b = (const float*)d_in[10];
    const float* W_A_w    = (const float*)d_in[11];
    const float* W_A_b    = (const float*)d_in[12];
    const float* W_str_w  = (const float*)d_in[13];
    const float* W_str_b  = (const float*)d_in[14];
    const float* ln_g     = (const float*)d_in[15];
    const float* ln_b     = (const float*)d_in[16];

    const int E = in_sizes[0] / 2;
    const int nNodes = in_sizes[1] / D;
    const int* srcI = edge;
    const int* tgtI = edge + E;

    float* ws = (float*)d_ws;
    size_t off = 0;
    float* alpha_den = ws + off; off += nNodes;
    float* beta_den  = ws + off; off += nNodes;
    float* sum_num   = ws + off; off += nNodes;
    int*   cnt       = (int*)(ws + off); off += nNodes;
    const size_t zero_bytes = off * sizeof(float);
    float* A         = ws + off; off += (size_t)nNodes * D;
    float* P         = ws + off; off += (size_t)nNodes * D;
    float* PP        = ws + off; off += (size_t)nNodes * D;
    float* PHI       = ws + off; off += (size_t)nNodes * D;
    float* psi       = ws + off; off += nNodes;
    float* inv_den   = ws + off; off += nNodes;
    float* w1m       = ws + off; off += nNodes;
    float* alpha_num = ws + off; off += E;
    int*   rank      = (int*)(ws + off); off += E;
    int*   rowstart  = (int*)(ws + off); off += nNodes + 1;
    int*   src_sorted= (int*)(ws + off); off += E;
    float* coeff_sorted = ws + off; off += E;

    hipMemsetAsync(d_ws, 0, zero_bytes, stream);

    node_pre_kernel<<<2048, 256, 0, stream>>>(
        h, W_att, W_p, W_pp, phi_w, phi_b, fdef_w, fdef_b,
        A, P, PP, PHI, psi, nNodes);

    hist_kernel<<<(E + 255) / 256, 256, 0, stream>>>(tgtI, cnt, rank, E);

    edge_pass1_kernel<<<8192, 256, 0, stream>>>(
        srcI, tgtI, h, A, P, PP, psi,
        alpha_num, alpha_den, beta_den, sum_num, E);

    scan_kernel<<<1, 1024, 0, stream>>>(cnt, rowstart, nNodes, E);

    node_mid_kernel<<<(nNodes + 255) / 256, 256, 0, stream>>>(
        alpha_den, beta_den, sum_num, inv_den, w1m, nNodes);

    scatter_kernel<<<(E + 255) / 256, 256, 0, stream>>>(
        srcI, tgtI, rank, rowstart, alpha_num, inv_den, w1m,
        src_sorted, coeff_sorted, E);

    gather_final_kernel<<<2048, 256, 0, stream>>>(
        rowstart, src_sorted, coeff_sorted, PHI, h,
        W_self_w, W_self_b, W_A_w, W_A_b, W_str_w, W_str_b,
        ln_g, ln_b, (float*)d_out, nNodes);
}

// Round 3
// 422.610 us; speedup vs baseline: 2.4030x; 1.1096x over previous
//
#include <hip/hip_runtime.h>
#include <hip/hip_fp16.h>
#include <math.h>

#define D 64

// ---------------- Kernel 1: per-node linear transforms ----------------
// AP16[n][j] = (A_j, P_j) fp16 pair; s6[n][0:8] = fp16 s_feat padded; PP f32;
// PHI16 = fp16(h@phi_w+b); psi[n] = h@fdef_w + fdef_b
__global__ __launch_bounds__(256) void node_pre_kernel(
    const float* __restrict__ h,
    const float* __restrict__ W_att,
    const float* __restrict__ W_p,
    const float* __restrict__ W_pp,
    const float* __restrict__ phi_w,
    const float* __restrict__ phi_b,
    const float* __restrict__ fdef_w,
    const float* __restrict__ fdef_b,
    __half2* __restrict__ AP16,
    __half* __restrict__ s6,
    float* __restrict__ PP,
    __half* __restrict__ PHI16,
    float* __restrict__ psi,
    int nNodes)
{
    __shared__ float sWatt[D * D];
    __shared__ float sWp[D * D];
    __shared__ float sWpp[D * D];
    __shared__ float sPhi[D * D];
    __shared__ float sPhib[D];
    __shared__ float sFdef[D];
    __shared__ float hrow[4][D];

    const int tid = threadIdx.x;
    for (int i = tid; i < D * D; i += 256) {
        sWatt[i] = W_att[i];
        sWp[i]   = W_p[i];
        sWpp[i]  = W_pp[i];
        sPhi[i]  = phi_w[i];
    }
    if (tid < D) { sPhib[tid] = phi_b[tid]; sFdef[tid] = fdef_w[tid]; }
    __syncthreads();
    const float fb = fdef_b[0];

    const int g = tid >> 6;
    const int j = tid & 63;

    for (int n0 = blockIdx.x * 4; n0 < nNodes; n0 += gridDim.x * 4) {
        const int n = n0 + g;
        __syncthreads();
        if (n < nNodes) hrow[g][j] = h[(size_t)n * D + j];
        __syncthreads();
        if (n < nNodes) {
            float a = 0.f, p = 0.f, pp = 0.f, ph = sPhib[j];
            #pragma unroll 8
            for (int k = 0; k < D; ++k) {
                const float hk = hrow[g][k];
                a  += hk * sWatt[k * D + j];
                p  += hk * sWp[k * D + j];
                pp += hk * sWpp[k * D + j];
                ph += hk * sPhi[k * D + j];
            }
            const size_t base = (size_t)n * D + j;
            AP16[base]  = __floats2half2_rn(a, p);
            PP[base]    = pp;
            PHI16[base] = __float2half(ph);
            if (j < 8) s6[(size_t)n * 8 + j] = __float2half(j < 6 ? hrow[g][j] : 0.f);
            float ps = hrow[g][j] * sFdef[j];
            #pragma unroll
            for (int off = 32; off >= 1; off >>= 1) ps += __shfl_xor(ps, off, 64);
            if (j == 0) psi[n] = ps + fb;
        }
    }
}

// ---------------- CSR build: histogram + rank ----------------
__global__ __launch_bounds__(256) void hist_kernel(
    const int* __restrict__ tgtI, int* __restrict__ cnt, int* __restrict__ rank, int nEdges)
{
    const int e = blockIdx.x * 256 + threadIdx.x;
    if (e < nEdges) rank[e] = atomicAdd(&cnt[tgtI[e]], 1);
}

// ---------------- CSR build: single-block exclusive scan ----------------
__global__ __launch_bounds__(1024) void scan_kernel(
    const int* __restrict__ cnt, int* __restrict__ rowstart, int nNodes, int nEdges)
{
    __shared__ int sums[1024];
    const int tid = threadIdx.x;
    const int per = (nNodes + 1023) / 1024;
    const int beg = tid * per;
    const int end = min(beg + per, nNodes);
    int s = 0;
    for (int i = beg; i < end; ++i) s += cnt[i];
    sums[tid] = s;
    __syncthreads();
    for (int off = 1; off < 1024; off <<= 1) {
        int add = (tid >= off) ? sums[tid - off] : 0;
        __syncthreads();
        sums[tid] += add;
        __syncthreads();
    }
    int run = sums[tid] - s;
    for (int i = beg; i < end; ++i) { rowstart[i] = run; run += cnt[i]; }
    if (tid == 1023) rowstart[nNodes] = nEdges;
}

// ---------------- CSR scatter: src ids sorted by tgt ----------------
__global__ __launch_bounds__(256) void scatter_src_kernel(
    const int* __restrict__ srcI,
    const int* __restrict__ tgtI,
    const int* __restrict__ rank,
    const int* __restrict__ rowstart,
    int* __restrict__ src_sorted,
    int nEdges)
{
    const int e = blockIdx.x * 256 + threadIdx.x;
    if (e >= nEdges) return;
    src_sorted[rowstart[tgtI[e]] + rank[e]] = srcI[e];
}

// ---------------- Pass 1 over tgt-CSR: one wave per tgt node ----------------
// score/pair dots; alpha_num in CSR order; alpha_den in-register -> inv_den;
// beta_den/sum_num via 2 atomics per edge.
__global__ __launch_bounds__(256) void pass1_csr_kernel(
    const int* __restrict__ rowstart,
    const int* __restrict__ src_sorted,
    const float* __restrict__ h,
    const __half2* __restrict__ AP16,
    const __half* __restrict__ s6,
    const float* __restrict__ PP,
    const float* __restrict__ psi,
    float* __restrict__ alpha_sorted,
    float* __restrict__ inv_den,
    float* __restrict__ beta_den,
    float* __restrict__ sum_num,
    int nNodes)
{
    const int wav = threadIdx.x >> 6;
    const int lane64 = threadIdx.x & 63;
    const int grp = lane64 >> 4;   // 4 edge-groups per wave
    const int l = lane64 & 15;     // 16 lanes per edge, 4 dims each

    for (int n = blockIdx.x * 4 + wav; n < nNodes; n += gridDim.x * 4) {
        const int beg = rowstart[n];
        const int end = rowstart[n + 1];
        const float4 htv = ((const float4*)(h  + (size_t)n * D))[l];
        const float4 ppv = ((const float4*)(PP + (size_t)n * D))[l];
        const float enpsi = __expf(-psi[n]);
        float aden = 0.f;

        for (int k = beg + grp; k < end; k += 4) {
            const int s = src_sorted[k];
            const float4 raw = *reinterpret_cast<const float4*>(
                (const char*)AP16 + ((size_t)s << 8) + (l << 4));
            const __half2 q0 = *reinterpret_cast<const __half2*>(&raw.x);
            const __half2 q1 = *reinterpret_cast<const __half2*>(&raw.y);
            const __half2 q2 = *reinterpret_cast<const __half2*>(&raw.z);
            const __half2 q3 = *reinterpret_cast<const __half2*>(&raw.w);

            float acc1 = __low2float(q0) * htv.x + __low2float(q1) * htv.y
                       + __low2float(q2) * htv.z + __low2float(q3) * htv.w;
            float acc2 = __high2float(q0) * ppv.x + __high2float(q1) * ppv.y
                       + __high2float(q2) * ppv.z + __high2float(q3) * ppv.w;

            if (l < 2) {  // structural dot: dims 0-5 (pads 6,7 are zero)
                const float2 sraw = *reinterpret_cast<const float2*>(
                    (const char*)s6 + ((size_t)s << 4) + (l << 3));
                const __half2 sa = *reinterpret_cast<const __half2*>(&sraw.x);
                const __half2 sb = *reinterpret_cast<const __half2*>(&sraw.y);
                acc1 += __low2float(sa) * htv.x + __high2float(sa) * htv.y
                      + __low2float(sb) * htv.z + __high2float(sb) * htv.w;
            }

            #pragma unroll
            for (int off = 8; off >= 1; off >>= 1) {
                acc1 += __shfl_xor(acc1, off, 64);
                acc2 += __shfl_xor(acc2, off, 64);
            }

            if (l == 0) {
                const float an = __expf(acc1);
                const float bn = __expf(acc2);
                alpha_sorted[k] = an;
                aden += an;
                atomicAdd(&beta_den[s], bn);
                atomicAdd(&sum_num[s], bn * enpsi);
            }
        }

        float ad = aden;  // nonzero only on l==0 lanes of each group
        #pragma unroll
        for (int off = 32; off >= 1; off >>= 1) ad += __shfl_xor(ad, off, 64);
        if (lane64 == 0) inv_den[n] = 1.0f / (ad + 1e-9f);
    }
}

// ---------------- Node mid: fold w1m into PHI -> PHIw16 ----------------
__global__ __launch_bounds__(256) void node_mid_kernel(
    const float* __restrict__ beta_den,
    const float* __restrict__ sum_num,
    const __half* __restrict__ PHI16,
    __half* __restrict__ PHIw16,
    int nNodes)
{
    const int wav = threadIdx.x >> 6;
    const int lane = threadIdx.x & 63;
    for (int n = blockIdx.x * 4 + wav; n < nNodes; n += gridDim.x * 4) {
        const float st = sum_num[n] / (beta_den[n] + 1e-9f);
        const float d = -logf(st + 1e-8f);
        const float w1m = 1.0f - 1.0f / (1.0f + __expf(-(d - 0.5f)));
        const size_t idx = (size_t)n * D + lane;
        PHIw16[idx] = __float2half(__half2float(PHI16[idx]) * w1m);
    }
}

// ---------------- Pass 2 fused: gather m_att + final matmuls + LN ----------------
__global__ __launch_bounds__(256) void gather_final_kernel(
    const int* __restrict__ rowstart,
    const int* __restrict__ src_sorted,
    const float* __restrict__ alpha_sorted,
    const float* __restrict__ inv_den,
    const __half* __restrict__ PHIw16,
    const float* __restrict__ h,
    const float* __restrict__ W_self_w, const float* __restrict__ W_self_b,
    const float* __restrict__ W_A_w,    const float* __restrict__ W_A_b,
    const float* __restrict__ W_str_w,  const float* __restrict__ W_str_b,
    const float* __restrict__ ln_g,     const float* __restrict__ ln_b,
    float* __restrict__ out,
    int nNodes)
{
    __shared__ float sWs[D * D];
    __shared__ float sWa[D * D];
    __shared__ float sWstr[6 * D];
    __shared__ float sBias[D];
    __shared__ float sG[D], sB[D];
    __shared__ float hrow[4][D];
    __shared__ float mrow[4][D];

    const int tid = threadIdx.x;
    for (int i = tid; i < D * D; i += 256) { sWs[i] = W_self_w[i]; sWa[i] = W_A_w[i]; }
    for (int i = tid; i < 6 * D; i += 256) sWstr[i] = W_str_w[i];
    if (tid < D) {
        sBias[tid] = W_self_b[tid] + W_A_b[tid] + W_str_b[tid];
        sG[tid] = ln_g[tid];
        sB[tid] = ln_b[tid];
    }
    __syncthreads();

    const int g = tid >> 6, j = tid & 63;
    for (int n0 = blockIdx.x * 4; n0 < nNodes; n0 += gridDim.x * 4) {
        const int n = n0 + g;
        __syncthreads();
        if (n < nNodes) {
            const int beg = rowstart[n];
            const int end = rowstart[n + 1];
            float acc = 0.f;
            int k = beg;
            for (; k + 3 < end; k += 4) {
                const int   s0 = src_sorted[k],     s1 = src_sorted[k + 1];
                const int   s2 = src_sorted[k + 2], s3 = src_sorted[k + 3];
                const float c0 = alpha_sorted[k],     c1 = alpha_sorted[k + 1];
                const float c2 = alpha_sorted[k + 2], c3 = alpha_sorted[k + 3];
                acc += c0 * __half2float(PHIw16[(size_t)s0 * D + j])
                     + c1 * __half2float(PHIw16[(size_t)s1 * D + j])
                     + c2 * __half2float(PHIw16[(size_t)s2 * D + j])
                     + c3 * __half2float(PHIw16[(size_t)s3 * D + j]);
            }
            for (; k < end; ++k)
                acc += alpha_sorted[k] * __half2float(PHIw16[(size_t)src_sorted[k] * D + j]);
            mrow[g][j] = acc * inv_den[n];
            hrow[g][j] = h[(size_t)n * D + j];
        }
        __syncthreads();
        if (n < nNodes) {
            float acc = sBias[j];
            #pragma unroll 8
            for (int k = 0; k < D; ++k)
                acc += hrow[g][k] * sWs[k * D + j] + mrow[g][k] * sWa[k * D + j];
            #pragma unroll
            for (int k = 0; k < 6; ++k)
                acc += hrow[g][k] * sWstr[k * D + j];

            float pre = fmaxf(acc, 0.f) + hrow[g][j];

            float mu = pre;
            #pragma unroll
            for (int off = 32; off >= 1; off >>= 1) mu += __shfl_xor(mu, off, 64);
            mu *= (1.0f / 64.0f);
            const float diff = pre - mu;
            float v = diff * diff;
            #pragma unroll
            for (int off = 32; off >= 1; off >>= 1) v += __shfl_xor(v, off, 64);
            v *= (1.0f / 64.0f);
            out[(size_t)n * D + j] = diff * rsqrtf(v + 1e-5f) * sG[j] + sB[j];
        }
    }
}

extern "C" void kernel_launch(void* const* d_in, const int* in_sizes, int n_in,
                              void* d_out, int out_size, void* d_ws, size_t ws_size,
                              hipStream_t stream) {
    const int* edge       = (const int*)d_in[0];
    const float* h        = (const float*)d_in[1];
    const float* W_att    = (const float*)d_in[2];
    const float* phi_w    = (const float*)d_in[3];
    const float* phi_b    = (const float*)d_in[4];
    const float* W_p      = (const float*)d_in[5];
    const float* W_pp     = (const float*)d_in[6];
    const float* fdef_w   = (const float*)d_in[7];
    const float* fdef_b   = (const float*)d_in[8];
    const float* W_self_w = (const float*)d_in[9];
    const float* W_self_b = (const float*)d_in[10];
    const float* W_A_w    = (const float*)d_in[11];
    const float* W_A_b    = (const float*)d_in[12];
    const float* W_str_w  = (const float*)d_in[13];
    const float* W_str_b  = (const float*)d_in[14];
    const float* ln_g     = (const float*)d_in[15];
    const float* ln_b     = (const float*)d_in[16];

    const int E = in_sizes[0] / 2;
    const int nNodes = in_sizes[1] / D;
    const int* srcI = edge;
    const int* tgtI = edge + E;

    char* ws = (char*)d_ws;
    size_t off = 0;
    auto alloc = [&](size_t bytes) { char* p = ws + off; off = (off + bytes + 255) & ~(size_t)255; return p; };

    int*    cnt       = (int*)   alloc((size_t)nNodes * 4);
    float*  beta_den  = (float*) alloc((size_t)nNodes * 4);
    float*  sum_num   = (float*) alloc((size_t)nNodes * 4);
    const size_t zero_bytes = off;
    __half2* AP16     = (__half2*)alloc((size_t)nNodes * D * 4);
    __half* s6        = (__half*) alloc((size_t)nNodes * 8 * 2);
    float*  PP        = (float*)  alloc((size_t)nNodes * D * 4);
    __half* PHI16     = (__half*) alloc((size_t)nNodes * D * 2);
    __half* PHIw16    = (__half*) alloc((size_t)nNodes * D * 2);
    float*  psi       = (float*)  alloc((size_t)nNodes * 4);
    float*  inv_den   = (float*)  alloc((size_t)nNodes * 4);
    int*    rank      = (int*)    alloc((size_t)E * 4);
    int*    rowstart  = (int*)    alloc(((size_t)nNodes + 1) * 4);
    int*    src_sorted= (int*)    alloc((size_t)E * 4);
    float*  alpha_sorted = (float*)alloc((size_t)E * 4);

    hipMemsetAsync(d_ws, 0, zero_bytes, stream);

    node_pre_kernel<<<2048, 256, 0, stream>>>(
        h, W_att, W_p, W_pp, phi_w, phi_b, fdef_w, fdef_b,
        AP16, s6, PP, PHI16, psi, nNodes);

    hist_kernel<<<(E + 255) / 256, 256, 0, stream>>>(tgtI, cnt, rank, E);

    scan_kernel<<<1, 1024, 0, stream>>>(cnt, rowstart, nNodes, E);

    scatter_src_kernel<<<(E + 255) / 256, 256, 0, stream>>>(
        srcI, tgtI, rank, rowstart, src_sorted, E);

    pass1_csr_kernel<<<(nNodes + 3) / 4, 256, 0, stream>>>(
        rowstart, src_sorted, h, AP16, s6, PP, psi,
        alpha_sorted, inv_den, beta_den, sum_num, nNodes);

    node_mid_kernel<<<(nNodes + 3) / 4, 256, 0, stream>>>(
        beta_den, sum_num, PHI16, PHIw16, nNodes);

    gather_final_kernel<<<(nNodes + 3) / 4, 256, 0, stream>>>(
        rowstart, src_sorted, alpha_sorted, inv_den, PHIw16, h,
        W_self_w, W_self_b, W_A_w, W_A_b, W_str_w, W_str_b,
        ln_g, ln_b, (float*)d_out, nNodes);
}

// Round 4
// 343.951 us; speedup vs baseline: 2.9526x; 1.2287x over previous
//
#include <hip/hip_runtime.h>
#include <math.h>

#define D 64

typedef _Float16 hf;
typedef _Float16 hf2 __attribute__((ext_vector_type(2)));

__device__ inline float fdot2f(hf2 a, hf2 b, float c) {
#if __has_builtin(__builtin_amdgcn_fdot2)
    return __builtin_amdgcn_fdot2(a, b, c, false);
#else
    return (float)a[0] * (float)b[0] + (float)a[1] * (float)b[1] + c;
#endif
}

// ---------------- Kernel 1: per-node linear transforms (fp16 weights, fdot2) ----------------
// AP16[n][j] = (A_j, P_j) fp16 pair; s6 fp16 x8; PP16 fp16; PHI16 fp16; psi f32.
__global__ __launch_bounds__(512) void node_pre_kernel(
    const float* __restrict__ h,
    const float* __restrict__ W_att,
    const float* __restrict__ W_p,
    const float* __restrict__ W_pp,
    const float* __restrict__ phi_w,
    const float* __restrict__ phi_b,
    const float* __restrict__ fdef_w,
    const float* __restrict__ fdef_b,
    hf2* __restrict__ AP16,
    hf* __restrict__ s6,
    hf* __restrict__ PP16,
    hf* __restrict__ PHI16,
    float* __restrict__ psi,
    int nNodes)
{
    // weight m, k-pair k2, col j : sW2[m][k2][j] = (W[2k2][j], W[2k2+1][j])
    __shared__ hf2 sW2[4][32][D];        // 32 KB
    __shared__ hf  hrowh[8][D];          // 1 KB
    __shared__ float sPhib[D];
    __shared__ float sFdef[D];

    const int tid = threadIdx.x;
    const float* Wm[4] = { W_att, W_p, W_pp, phi_w };
    for (int idx = tid; idx < 4 * 32 * D; idx += 512) {
        const int m  = idx >> 11;
        const int k2 = (idx >> 6) & 31;
        const int j  = idx & 63;
        const float w0 = Wm[m][(2 * k2) * D + j];
        const float w1 = Wm[m][(2 * k2 + 1) * D + j];
        sW2[m][k2][j] = hf2{(hf)w0, (hf)w1};
    }
    if (tid < D) { sPhib[tid] = phi_b[tid]; sFdef[tid] = fdef_w[tid]; }
    __syncthreads();
    const float fb = fdef_b[0];

    const int g = tid >> 6;    // wave 0..7
    const int j = tid & 63;

    for (int n0 = blockIdx.x * 8; n0 < nNodes; n0 += gridDim.x * 8) {
        const int n = n0 + g;
        float hj = 0.f;
        __syncthreads();
        if (n < nNodes) {
            hj = h[(size_t)n * D + j];
            hrowh[g][j] = (hf)hj;
        }
        __syncthreads();
        if (n < nNodes) {
            float a = 0.f, p = 0.f, pp = 0.f, ph = sPhib[j];
            const hf2* hr = (const hf2*)hrowh[g];
            #pragma unroll
            for (int k2 = 0; k2 < 32; ++k2) {
                const hf2 hb = hr[k2];
                a  = fdot2f(sW2[0][k2][j], hb, a);
                p  = fdot2f(sW2[1][k2][j], hb, p);
                pp = fdot2f(sW2[2][k2][j], hb, pp);
                ph = fdot2f(sW2[3][k2][j], hb, ph);
            }
            const size_t base = (size_t)n * D + j;
            AP16[base]  = hf2{(hf)a, (hf)p};
            PP16[base]  = (hf)pp;
            PHI16[base] = (hf)ph;
            if (j < 8) s6[(size_t)n * 8 + j] = (hf)(j < 6 ? hj : 0.f);
            float ps = hj * sFdef[j];
            #pragma unroll
            for (int off = 32; off >= 1; off >>= 1) ps += __shfl_xor(ps, off, 64);
            if (j == 0) psi[n] = ps + fb;
        }
    }
}

// ---------------- CSR build: histogram + rank ----------------
__global__ __launch_bounds__(256) void hist_kernel(
    const int* __restrict__ tgtI, int* __restrict__ cnt, int* __restrict__ rank, int nEdges)
{
    const int e = blockIdx.x * 256 + threadIdx.x;
    if (e < nEdges) rank[e] = atomicAdd(&cnt[tgtI[e]], 1);
}

// ---------------- CSR build: single-block exclusive scan ----------------
__global__ __launch_bounds__(1024) void scan_kernel(
    const int* __restrict__ cnt, int* __restrict__ rowstart, int nNodes, int nEdges)
{
    __shared__ int sums[1024];
    const int tid = threadIdx.x;
    const int per = (nNodes + 1023) / 1024;
    const int beg = tid * per;
    const int end = min(beg + per, nNodes);
    int s = 0;
    for (int i = beg; i < end; ++i) s += cnt[i];
    sums[tid] = s;
    __syncthreads();
    for (int off = 1; off < 1024; off <<= 1) {
        int add = (tid >= off) ? sums[tid - off] : 0;
        __syncthreads();
        sums[tid] += add;
        __syncthreads();
    }
    int run = sums[tid] - s;
    for (int i = beg; i < end; ++i) { rowstart[i] = run; run += cnt[i]; }
    if (tid == 1023) rowstart[nNodes] = nEdges;
}

// ---------------- CSR scatter: src ids sorted by tgt ----------------
__global__ __launch_bounds__(256) void scatter_src_kernel(
    const int* __restrict__ srcI,
    const int* __restrict__ tgtI,
    const int* __restrict__ rank,
    const int* __restrict__ rowstart,
    int* __restrict__ src_sorted,
    int nEdges)
{
    const int e = blockIdx.x * 256 + threadIdx.x;
    if (e >= nEdges) return;
    src_sorted[rowstart[tgtI[e]] + rank[e]] = srcI[e];
}

// ---------------- Pass 1 over tgt-CSR: one wave per tgt node ----------------
__global__ __launch_bounds__(256) void pass1_csr_kernel(
    const int* __restrict__ rowstart,
    const int* __restrict__ src_sorted,
    const float* __restrict__ h,
    const hf2* __restrict__ AP16,
    const hf* __restrict__ s6,
    const hf* __restrict__ PP16,
    const float* __restrict__ psi,
    float* __restrict__ alpha_sorted,
    float* __restrict__ inv_den,
    float* __restrict__ beta_den,
    float* __restrict__ sum_num,
    int nNodes)
{
    const int wav = threadIdx.x >> 6;
    const int lane64 = threadIdx.x & 63;
    const int grp = lane64 >> 4;   // 4 edge-groups per wave
    const int l = lane64 & 15;     // 16 lanes per edge, 4 dims each

    for (int n = blockIdx.x * 4 + wav; n < nNodes; n += gridDim.x * 4) {
        const int beg = rowstart[n];
        const int end = rowstart[n + 1];
        const float4 htv = ((const float4*)(h + (size_t)n * D))[l];
        // own PP row: dims 4l..4l+3 as fp16
        const float2 ppraw = *reinterpret_cast<const float2*>(
            (const char*)PP16 + ((size_t)n << 7) + (l << 3));
        const hf* ppq = (const hf*)&ppraw;
        const float pp0 = ppq[0], pp1 = ppq[1], pp2 = ppq[2], pp3 = ppq[3];
        const float enpsi = __expf(-psi[n]);
        float aden = 0.f;

        for (int k = beg + grp; k < end; k += 4) {
            const int s = src_sorted[k];
            const float4 raw = *reinterpret_cast<const float4*>(
                (const char*)AP16 + ((size_t)s << 8) + (l << 4));
            const hf* q = (const hf*)&raw;   // interleaved A,P x4

            float acc1 = (float)q[0] * htv.x + (float)q[2] * htv.y
                       + (float)q[4] * htv.z + (float)q[6] * htv.w;
            float acc2 = (float)q[1] * pp0 + (float)q[3] * pp1
                       + (float)q[5] * pp2 + (float)q[7] * pp3;

            if (l < 2) {  // structural dot: dims 0-5 (pads 6,7 zero)
                const float2 sraw = *reinterpret_cast<const float2*>(
                    (const char*)s6 + ((size_t)s << 4) + (l << 3));
                const hf* sq = (const hf*)&sraw;
                acc1 += (float)sq[0] * htv.x + (float)sq[1] * htv.y
                      + (float)sq[2] * htv.z + (float)sq[3] * htv.w;
            }

            #pragma unroll
            for (int off = 8; off >= 1; off >>= 1) {
                acc1 += __shfl_xor(acc1, off, 64);
                acc2 += __shfl_xor(acc2, off, 64);
            }

            if (l == 0) {
                const float an = __expf(acc1);
                const float bn = __expf(acc2);
                alpha_sorted[k] = an;
                aden += an;
                atomicAdd(&beta_den[s], bn);
                atomicAdd(&sum_num[s], bn * enpsi);
            }
        }

        float ad = aden;
        #pragma unroll
        for (int off = 32; off >= 1; off >>= 1) ad += __shfl_xor(ad, off, 64);
        if (lane64 == 0) inv_den[n] = 1.0f / (ad + 1e-9f);
    }
}

// ---------------- Node mid: fold w1m into PHI -> PHIw16 ----------------
__global__ __launch_bounds__(256) void node_mid_kernel(
    const float* __restrict__ beta_den,
    const float* __restrict__ sum_num,
    const hf* __restrict__ PHI16,
    hf* __restrict__ PHIw16,
    int nNodes)
{
    const int wav = threadIdx.x >> 6;
    const int lane = threadIdx.x & 63;
    for (int n = blockIdx.x * 4 + wav; n < nNodes; n += gridDim.x * 4) {
        const float st = sum_num[n] / (beta_den[n] + 1e-9f);
        const float d = -logf(st + 1e-8f);
        const float w1m = 1.0f - 1.0f / (1.0f + __expf(-(d - 0.5f)));
        const size_t idx = (size_t)n * D + lane;
        PHIw16[idx] = (hf)((float)PHI16[idx] * w1m);
    }
}

// ---------------- Gather m_att (no LDS, max occupancy) ----------------
__global__ __launch_bounds__(256) void gather_m_kernel(
    const int* __restrict__ rowstart,
    const int* __restrict__ src_sorted,
    const float* __restrict__ alpha_sorted,
    const float* __restrict__ inv_den,
    const hf* __restrict__ PHIw16,
    hf* __restrict__ m16,
    int nNodes)
{
    const int g = threadIdx.x >> 6;
    const int j = threadIdx.x & 63;
    for (int n = blockIdx.x * 4 + g; n < nNodes; n += gridDim.x * 4) {
        const int beg = rowstart[n];
        const int end = rowstart[n + 1];
        float acc = 0.f;
        int k = beg;
        for (; k + 3 < end; k += 4) {
            const int   s0 = src_sorted[k],     s1 = src_sorted[k + 1];
            const int   s2 = src_sorted[k + 2], s3 = src_sorted[k + 3];
            const float c0 = alpha_sorted[k],     c1 = alpha_sorted[k + 1];
            const float c2 = alpha_sorted[k + 2], c3 = alpha_sorted[k + 3];
            acc += c0 * (float)PHIw16[(size_t)s0 * D + j]
                 + c1 * (float)PHIw16[(size_t)s1 * D + j]
                 + c2 * (float)PHIw16[(size_t)s2 * D + j]
                 + c3 * (float)PHIw16[(size_t)s3 * D + j];
        }
        for (; k < end; ++k)
            acc += alpha_sorted[k] * (float)PHIw16[(size_t)src_sorted[k] * D + j];
        m16[(size_t)n * D + j] = (hf)(acc * inv_den[n]);
    }
}

// ---------------- Final: fused matmuls (fp16 weights, fdot2) + relu + residual + LN ----------------
__global__ __launch_bounds__(512) void final_kernel(
    const float* __restrict__ h,
    const hf* __restrict__ m16,
    const float* __restrict__ W_self_w, const float* __restrict__ W_self_b,
    const float* __restrict__ W_A_w,    const float* __restrict__ W_A_b,
    const float* __restrict__ W_str_w,  const float* __restrict__ W_str_b,
    const float* __restrict__ ln_g,     const float* __restrict__ ln_b,
    float* __restrict__ out,
    int nNodes)
{
    __shared__ hf2 sWs2[32][D];     // 8 KB
    __shared__ hf2 sWa2[32][D];     // 8 KB
    __shared__ float sWstr[6 * D];
    __shared__ float sBias[D];
    __shared__ float sG[D], sB[D];
    __shared__ hf hrowh[8][D];
    __shared__ hf mrowh[8][D];

    const int tid = threadIdx.x;
    for (int idx = tid; idx < 32 * D; idx += 512) {
        const int k2 = idx >> 6, j = idx & 63;
        sWs2[k2][j] = hf2{(hf)W_self_w[(2 * k2) * D + j], (hf)W_self_w[(2 * k2 + 1) * D + j]};
        sWa2[k2][j] = hf2{(hf)W_A_w[(2 * k2) * D + j],    (hf)W_A_w[(2 * k2 + 1) * D + j]};
    }
    for (int i = tid; i < 6 * D; i += 512) sWstr[i] = W_str_w[i];
    if (tid < D) {
        sBias[tid] = W_self_b[tid] + W_A_b[tid] + W_str_b[tid];
        sG[tid] = ln_g[tid];
        sB[tid] = ln_b[tid];
    }
    __syncthreads();

    const int g = tid >> 6, j = tid & 63;
    for (int n0 = blockIdx.x * 8; n0 < nNodes; n0 += gridDim.x * 8) {
        const int n = n0 + g;
        float hj = 0.f;
        __syncthreads();
        if (n < nNodes) {
            hj = h[(size_t)n * D + j];
            hrowh[g][j] = (hf)hj;
            mrowh[g][j] = m16[(size_t)n * D + j];
        }
        __syncthreads();
        if (n < nNodes) {
            float acc = sBias[j];
            const hf2* hr = (const hf2*)hrowh[g];
            const hf2* mr = (const hf2*)mrowh[g];
            #pragma unroll
            for (int k2 = 0; k2 < 32; ++k2) {
                acc = fdot2f(sWs2[k2][j], hr[k2], acc);
                acc = fdot2f(sWa2[k2][j], mr[k2], acc);
            }
            #pragma unroll
            for (int k = 0; k < 6; ++k)
                acc += (float)hrowh[g][k] * sWstr[k * D + j];

            float pre = fmaxf(acc, 0.f) + hj;

            float mu = pre;
            #pragma unroll
            for (int off = 32; off >= 1; off >>= 1) mu += __shfl_xor(mu, off, 64);
            mu *= (1.0f / 64.0f);
            const float diff = pre - mu;
            float v = diff * diff;
            #pragma unroll
            for (int off = 32; off >= 1; off >>= 1) v += __shfl_xor(v, off, 64);
            v *= (1.0f / 64.0f);
            out[(size_t)n * D + j] = diff * rsqrtf(v + 1e-5f) * sG[j] + sB[j];
        }
    }
}

extern "C" void kernel_launch(void* const* d_in, const int* in_sizes, int n_in,
                              void* d_out, int out_size, void* d_ws, size_t ws_size,
                              hipStream_t stream) {
    const int* edge       = (const int*)d_in[0];
    const float* h        = (const float*)d_in[1];
    const float* W_att    = (const float*)d_in[2];
    const float* phi_w    = (const float*)d_in[3];
    const float* phi_b    = (const float*)d_in[4];
    const float* W_p      = (const float*)d_in[5];
    const float* W_pp     = (const float*)d_in[6];
    const float* fdef_w   = (const float*)d_in[7];
    const float* fdef_b   = (const float*)d_in[8];
    const float* W_self_w = (const float*)d_in[9];
    const float* W_self_b = (const float*)d_in[10];
    const float* W_A_w    = (const float*)d_in[11];
    const float* W_A_b    = (const float*)d_in[12];
    const float* W_str_w  = (const float*)d_in[13];
    const float* W_str_b  = (const float*)d_in[14];
    const float* ln_g     = (const float*)d_in[15];
    const float* ln_b     = (const float*)d_in[16];

    const int E = in_sizes[0] / 2;
    const int nNodes = in_sizes[1] / D;
    const int* srcI = edge;
    const int* tgtI = edge + E;

    char* ws = (char*)d_ws;
    size_t off = 0;
    auto alloc = [&](size_t bytes) { char* p = ws + off; off = (off + bytes + 255) & ~(size_t)255; return p; };

    int*    cnt       = (int*)   alloc((size_t)nNodes * 4);
    float*  beta_den  = (float*) alloc((size_t)nNodes * 4);
    float*  sum_num   = (float*) alloc((size_t)nNodes * 4);
    const size_t zero_bytes = off;
    hf2*    AP16      = (hf2*)   alloc((size_t)nNodes * D * 4);
    hf*     s6        = (hf*)    alloc((size_t)nNodes * 8 * 2);
    hf*     PP16      = (hf*)    alloc((size_t)nNodes * D * 2);
    hf*     PHI16     = (hf*)    alloc((size_t)nNodes * D * 2);
    hf*     PHIw16    = (hf*)    alloc((size_t)nNodes * D * 2);
    hf*     m16       = (hf*)    alloc((size_t)nNodes * D * 2);
    float*  psi       = (float*) alloc((size_t)nNodes * 4);
    float*  inv_den   = (float*) alloc((size_t)nNodes * 4);
    int*    rank      = (int*)   alloc((size_t)E * 4);
    int*    rowstart  = (int*)   alloc(((size_t)nNodes + 1) * 4);
    int*    src_sorted= (int*)   alloc((size_t)E * 4);
    float*  alpha_sorted = (float*)alloc((size_t)E * 4);

    hipMemsetAsync(d_ws, 0, zero_bytes, stream);

    node_pre_kernel<<<2048, 512, 0, stream>>>(
        h, W_att, W_p, W_pp, phi_w, phi_b, fdef_w, fdef_b,
        AP16, s6, PP16, PHI16, psi, nNodes);

    hist_kernel<<<(E + 255) / 256, 256, 0, stream>>>(tgtI, cnt, rank, E);

    scan_kernel<<<1, 1024, 0, stream>>>(cnt, rowstart, nNodes, E);

    scatter_src_kernel<<<(E + 255) / 256, 256, 0, stream>>>(
        srcI, tgtI, rank, rowstart, src_sorted, E);

    pass1_csr_kernel<<<(nNodes + 3) / 4, 256, 0, stream>>>(
        rowstart, src_sorted, h, AP16, s6, PP16, psi,
        alpha_sorted, inv_den, beta_den, sum_num, nNodes);

    node_mid_kernel<<<(nNodes + 3) / 4, 256, 0, stream>>>(
        beta_den, sum_num, PHI16, PHIw16, nNodes);

    gather_m_kernel<<<2048, 256, 0, stream>>>(
        rowstart, src_sorted, alpha_sorted, inv_den, PHIw16, m16, nNodes);

    final_kernel<<<2048, 512, 0, stream>>>(
        h, m16, W_self_w, W_self_b, W_A_w, W_A_b,
        W_str_w, W_str_b, ln_g, ln_b, (float*)d_out, nNodes);
}